// Round 1
// baseline (281.809 us; speedup 1.0000x reference)
//
#include <hip/hip_runtime.h>
#include <limits.h>
#include <math.h>

// Problem constants (fixed by setup_inputs): x[128][262144] fp32, topk=5.
#define BROWS 128
#define NCOLS (256 * 32 * 32)      // 262144 elements per row
#define K 5
#define BPR 16                     // blocks per row
#define TPB 256                    // threads per block
#define CHUNK (NCOLS / BPR)        // 16384 elements per block
#define CHUNK4 (CHUNK / 4)         // 4096 float4 per block
#define F4_PER_THREAD (CHUNK4 / TPB) // 16 float4 per thread

__device__ __forceinline__ bool better(float av, int ai, float bv, int bi) {
    // total order: value desc, then index asc (matches jax.lax.top_k ties)
    return (av > bv) || (av == bv && ai < bi);
}

// Insert candidate into a sorted-descending top-K list. Fully unrolled,
// constant indices only -> stays in VGPRs. Fast path: 1 compare.
__device__ __forceinline__ void insert5(float (&v)[K], int (&ix)[K], float cv, int ci) {
    if (better(cv, ci, v[K - 1], ix[K - 1])) {
        v[K - 1] = cv; ix[K - 1] = ci;
#pragma unroll
        for (int s = K - 1; s > 0; --s) {
            if (better(v[s], ix[s], v[s - 1], ix[s - 1])) {
                float tv = v[s]; v[s] = v[s - 1]; v[s - 1] = tv;
                int ti = ix[s]; ix[s] = ix[s - 1]; ix[s - 1] = ti;
            }
        }
    }
}

__device__ __forceinline__ void wave_reduce5(float (&v)[K], int (&ix)[K]) {
#pragma unroll
    for (int off = 1; off < 64; off <<= 1) {
        float ov[K]; int oi[K];
#pragma unroll
        for (int k = 0; k < K; ++k) {
            ov[k] = __shfl_xor(v[k], off, 64);
            oi[k] = __shfl_xor(ix[k], off, 64);
        }
#pragma unroll
        for (int k = 0; k < K; ++k) insert5(v, ix, ov[k], oi[k]);
    }
}

// Kernel 1: stream x (read) + zero out (write) in one pass; per-block top-5
// candidates -> workspace.
__global__ __launch_bounds__(TPB) void wta_scan(const float* __restrict__ x,
                                                float* __restrict__ out,
                                                float* __restrict__ wsv,
                                                int* __restrict__ wsi) {
    const int gb  = blockIdx.x;
    const int row = gb / BPR;
    const int blk = gb % BPR;
    const size_t base = (size_t)row * NCOLS + (size_t)blk * CHUNK;
    const float4* __restrict__ x4 = (const float4*)(x + base);
    float4* __restrict__ o4 = (float4*)(out + base);
    const int t = threadIdx.x;

    float v[K]; int ix[K];
#pragma unroll
    for (int k = 0; k < K; ++k) { v[k] = -INFINITY; ix[k] = INT_MAX; }

    const float4 z = make_float4(0.f, 0.f, 0.f, 0.f);
#pragma unroll
    for (int i = 0; i < F4_PER_THREAD; ++i) {
        const int e4 = t + i * TPB;            // coalesced: lane-contiguous
        const float4 d = x4[e4];
        o4[e4] = z;
        const int e = blk * CHUNK + e4 * 4;    // column index within the row
        insert5(v, ix, d.x, e + 0);
        insert5(v, ix, d.y, e + 1);
        insert5(v, ix, d.z, e + 2);
        insert5(v, ix, d.w, e + 3);
    }

    wave_reduce5(v, ix);

    __shared__ float sv[TPB / 64][K];
    __shared__ int   si[TPB / 64][K];
    const int wave = t >> 6, lane = t & 63;
    if (lane == 0) {
#pragma unroll
        for (int k = 0; k < K; ++k) { sv[wave][k] = v[k]; si[wave][k] = ix[k]; }
    }
    __syncthreads();
    if (t == 0) {
#pragma unroll
        for (int w = 1; w < TPB / 64; ++w)
#pragma unroll
            for (int k = 0; k < K; ++k) insert5(v, ix, sv[w][k], si[w][k]);
        const int o = gb * K;
#pragma unroll
        for (int k = 0; k < K; ++k) { wsv[o + k] = v[k]; wsi[o + k] = ix[k]; }
    }
}

// Kernel 2: per row, merge BPR*K=80 candidates, scatter five 1.0f stores.
__global__ __launch_bounds__(64) void wta_final(const float* __restrict__ wsv,
                                                const int* __restrict__ wsi,
                                                float* __restrict__ out) {
    const int row  = blockIdx.x;
    const int lane = threadIdx.x;

    float v[K]; int ix[K];
#pragma unroll
    for (int k = 0; k < K; ++k) { v[k] = -INFINITY; ix[k] = INT_MAX; }

    const int ncand = BPR * K; // 80
    for (int c = lane; c < ncand; c += 64)
        insert5(v, ix, wsv[row * ncand + c], wsi[row * ncand + c]);

    wave_reduce5(v, ix);

    if (lane == 0) {
#pragma unroll
        for (int k = 0; k < K; ++k)
            out[(size_t)row * NCOLS + ix[k]] = 1.0f;
    }
}

extern "C" void kernel_launch(void* const* d_in, const int* in_sizes, int n_in,
                              void* d_out, int out_size, void* d_ws, size_t ws_size,
                              hipStream_t stream) {
    const float* x = (const float*)d_in[0];
    // d_in[1] is topk (==5 always); K is compile-time.
    float* out = (float*)d_out;
    float* wsv = (float*)d_ws;                                  // 2048*5 floats
    int*   wsi = (int*)((char*)d_ws + (size_t)BROWS * BPR * K * sizeof(float));

    wta_scan<<<BROWS * BPR, TPB, 0, stream>>>(x, out, wsv, wsi);
    wta_final<<<BROWS, 64, 0, stream>>>(wsv, wsi, out);
}

// Round 2
// 254.956 us; speedup vs baseline: 1.1053x; 1.1053x over previous
//
#include <hip/hip_runtime.h>
#include <limits.h>
#include <math.h>

// Problem constants (fixed by setup_inputs): x[128][262144] fp32, topk=5.
#define BROWS 128
#define NCOLS (256 * 32 * 32)        // 262144 elements per row
#define K 5
#define BPR 32                       // blocks per row
#define TPB 256                      // threads per block
#define CHUNK (NCOLS / BPR)          // 8192 elements per block
#define F4_PER_THREAD (CHUNK / 4 / TPB) // 8 float4 per thread

__device__ __forceinline__ bool better(float av, int ai, float bv, int bi) {
    // total order: value desc, then index asc (matches jax.lax.top_k ties)
    return (av > bv) || (av == bv && ai < bi);
}

// Insert candidate into a sorted-descending top-K list. Fully unrolled,
// constant indices only -> stays in VGPRs.
__device__ __forceinline__ void insert5(float (&v)[K], int (&ix)[K], float cv, int ci) {
    if (better(cv, ci, v[K - 1], ix[K - 1])) {
        v[K - 1] = cv; ix[K - 1] = ci;
#pragma unroll
        for (int s = K - 1; s > 0; --s) {
            if (better(v[s], ix[s], v[s - 1], ix[s - 1])) {
                float tv = v[s]; v[s] = v[s - 1]; v[s - 1] = tv;
                int ti = ix[s]; ix[s] = ix[s - 1]; ix[s - 1] = ti;
            }
        }
    }
}

__device__ __forceinline__ void wave_reduce5(float (&v)[K], int (&ix)[K]) {
#pragma unroll
    for (int off = 1; off < 64; off <<= 1) {
        float ov[K]; int oi[K];
#pragma unroll
        for (int k = 0; k < K; ++k) {
            ov[k] = __shfl_xor(v[k], off, 64);
            oi[k] = __shfl_xor(ix[k], off, 64);
        }
#pragma unroll
        for (int k = 0; k < K; ++k) insert5(v, ix, ov[k], oi[k]);
    }
}

// Kernel 1: stream x (read) + zero out (write) in one pass; per-block top-5
// candidates -> workspace. Batched loads for memory-level parallelism; max4
// fast-path guard so the hot loop is 3 v_max + 1 v_cmp per 4 elements.
__global__ __launch_bounds__(TPB) void wta_scan(const float* __restrict__ x,
                                                float* __restrict__ out,
                                                float* __restrict__ wsv,
                                                int* __restrict__ wsi) {
    const int gb  = blockIdx.x;
    const int row = gb / BPR;
    const int blk = gb % BPR;
    const size_t base = (size_t)row * NCOLS + (size_t)blk * CHUNK;
    const float4* __restrict__ x4 = (const float4*)(x + base);
    float4* __restrict__ o4 = (float4*)(out + base);
    const int t = threadIdx.x;

    // Batch all loads first: 8 outstanding 16B/lane loads per wave.
    float4 r[F4_PER_THREAD];
#pragma unroll
    for (int i = 0; i < F4_PER_THREAD; ++i) r[i] = x4[t + i * TPB];

    const float4 z = make_float4(0.f, 0.f, 0.f, 0.f);
#pragma unroll
    for (int i = 0; i < F4_PER_THREAD; ++i) o4[t + i * TPB] = z;

    float v[K]; int ix[K];
#pragma unroll
    for (int k = 0; k < K; ++k) { v[k] = -INFINITY; ix[k] = INT_MAX; }

#pragma unroll
    for (int i = 0; i < F4_PER_THREAD; ++i) {
        const float4 d = r[i];
        const float m = fmaxf(fmaxf(d.x, d.y), fmaxf(d.z, d.w));
        // Guard is a superset of the insert condition (ties included via >=),
        // so the slow path's exact better() preserves semantics.
        if (m >= v[K - 1]) {
            const int e = blk * CHUNK + (t + i * TPB) * 4;
            insert5(v, ix, d.x, e + 0);
            insert5(v, ix, d.y, e + 1);
            insert5(v, ix, d.z, e + 2);
            insert5(v, ix, d.w, e + 3);
        }
    }

    wave_reduce5(v, ix);

    __shared__ float sv[TPB / 64][K];
    __shared__ int   si[TPB / 64][K];
    const int wave = t >> 6, lane = t & 63;
    if (lane == 0) {
#pragma unroll
        for (int k = 0; k < K; ++k) { sv[wave][k] = v[k]; si[wave][k] = ix[k]; }
    }
    __syncthreads();
    if (t == 0) {
#pragma unroll
        for (int w = 1; w < TPB / 64; ++w)
#pragma unroll
            for (int k = 0; k < K; ++k) insert5(v, ix, sv[w][k], si[w][k]);
        const int o = gb * K;
#pragma unroll
        for (int k = 0; k < K; ++k) { wsv[o + k] = v[k]; wsi[o + k] = ix[k]; }
    }
}

// Kernel 2: per row, merge BPR*K=160 candidates, scatter five 1.0f stores.
__global__ __launch_bounds__(64) void wta_final(const float* __restrict__ wsv,
                                                const int* __restrict__ wsi,
                                                float* __restrict__ out) {
    const int row  = blockIdx.x;
    const int lane = threadIdx.x;

    float v[K]; int ix[K];
#pragma unroll
    for (int k = 0; k < K; ++k) { v[k] = -INFINITY; ix[k] = INT_MAX; }

    const int ncand = BPR * K; // 160
    for (int c = lane; c < ncand; c += 64)
        insert5(v, ix, wsv[row * ncand + c], wsi[row * ncand + c]);

    wave_reduce5(v, ix);

    if (lane == 0) {
#pragma unroll
        for (int k = 0; k < K; ++k)
            out[(size_t)row * NCOLS + ix[k]] = 1.0f;
    }
}

extern "C" void kernel_launch(void* const* d_in, const int* in_sizes, int n_in,
                              void* d_out, int out_size, void* d_ws, size_t ws_size,
                              hipStream_t stream) {
    const float* x = (const float*)d_in[0];
    // d_in[1] is topk (==5 always); K is compile-time.
    float* out = (float*)d_out;
    float* wsv = (float*)d_ws;                                  // 4096*5 floats
    int*   wsi = (int*)((char*)d_ws + (size_t)BROWS * BPR * K * sizeof(float));

    wta_scan<<<BROWS * BPR, TPB, 0, stream>>>(x, out, wsv, wsi);
    wta_final<<<BROWS, 64, 0, stream>>>(wsv, wsi, out);
}